// Round 7
// baseline (1020.508 us; speedup 1.0000x reference)
//
#include <hip/hip_runtime.h>

#define EPS 1e-6f

typedef __attribute__((ext_vector_type(4))) unsigned short us4;
typedef __attribute__((ext_vector_type(8))) unsigned short us8;
typedef __attribute__((ext_vector_type(4))) __bf16 bf16x4;
typedef __attribute__((ext_vector_type(8))) __bf16 bf16x8;
typedef __attribute__((ext_vector_type(4))) float f32x4;

// Native f32->bf16 (RTN-even); gfx950 lowers pairs to v_cvt_pk_bf16_f32.
__device__ __forceinline__ us8 cvt8(float4 a, float4 b) {
  bf16x8 r;
  r[0] = (__bf16)a.x; r[1] = (__bf16)a.y; r[2] = (__bf16)a.z; r[3] = (__bf16)a.w;
  r[4] = (__bf16)b.x; r[5] = (__bf16)b.y; r[6] = (__bf16)b.z; r[7] = (__bf16)b.w;
  return __builtin_bit_cast(us8, r);
}

// Shared per-K-step MFMA: A in Al[128][32] bf16 (row-major, 16B-block XOR swizzle),
// B in Bl[32][128] bf16 (row-major, 16-col-block XOR by k-octet-group).
// A-frag: ds_read_b128; B-frag: 8x ds_read_u16 column gather. Natural k-order both sides.
__device__ __forceinline__ void mfma_step(const unsigned short* Al, const unsigned short* Bl,
                                          int wr, int wc, int ln, int lg, f32x4 acc[4][4]) {
  us8 af[4];
#pragma unroll
  for (int mi = 0; mi < 4; ++mi) {
    int m = (wr << 6) + (mi << 4) + ln;
    af[mi] = *(const us8*)&Al[m * 32 + ((lg ^ ((m >> 1) & 3)) << 3)];
  }
#pragma unroll
  for (int ni = 0; ni < 4; ++ni) {
    int nc = (wc << 6) + (ni << 4) + ln;
    const unsigned short* bp = &Bl[(lg << 3) * 128 + (nc ^ (lg << 4))];
    us8 bv;
#pragma unroll
    for (int j = 0; j < 8; ++j) bv[j] = bp[j * 128];
#pragma unroll
    for (int mi = 0; mi < 4; ++mi)
      acc[mi][ni] = __builtin_amdgcn_mfma_f32_16x16x32_bf16(
          __builtin_bit_cast(bf16x8, af[mi]), __builtin_bit_cast(bf16x8, bv),
          acc[mi][ni], 0, 0, 0);
  }
}

// ---- K0: transpose X[n][128] -> XT[128][n] (XT lives in d_out) ----
__global__ void k_tr(const float* __restrict__ X, float* __restrict__ XT, int n) {
  __shared__ float tl[32][33];
  int t = threadIdx.x, tx = t & 31, ty = t >> 5;
  int i0 = blockIdx.x << 5, f0 = blockIdx.y << 5;
#pragma unroll
  for (int r = 0; r < 4; ++r)
    tl[ty + (r << 3)][tx] = X[(size_t)(i0 + ty + (r << 3)) * 128 + f0 + tx];
  __syncthreads();
#pragma unroll
  for (int r = 0; r < 4; ++r)
    XT[(size_t)(f0 + ty + (r << 3)) * n + i0 + tx] = tl[tx][ty + (r << 3)];
}

// ---- K1: MT[128][e] += XT(128 x Kslice) * H(Kslice x e-tile); deg_e += colsums(H) ----
__global__ __launch_bounds__(256, 2) void k_gemm1(const float* __restrict__ XT,
                                                  const float* __restrict__ H,
                                                  float* __restrict__ MT,
                                                  float* __restrict__ dege, int n, int e) {
  __shared__ __align__(16) unsigned char smem[16384];
  unsigned short* Al = (unsigned short*)smem;
  unsigned short* Bl = (unsigned short*)(smem + 8192);
  const int t = threadIdx.x;
  const int lane = t & 63, ln = lane & 15, lg = lane >> 4;
  const int wid = t >> 6, wr = wid >> 1, wc = wid & 1;
  const int j0 = blockIdx.x << 7;
  const int nsteps = n >> 5;
  const int s0 = (nsteps * (int)blockIdx.y) >> 3;
  const int s1 = (nsteps * ((int)blockIdx.y + 1)) >> 3;

  const int am = t >> 2, ao = t & 3;          // A: rows am, am+64; k-octet ao
  const int bk = t >> 4, bn = (t & 15) << 3;  // B: k-rows bk, bk+16; n-octet bn
  const bool bok = (j0 + bn) < e;

  float4 a0, a1, a2, a3, b0, b1, b2, b3;
  float dacc[8];
#pragma unroll
  for (int c = 0; c < 8; ++c) dacc[c] = 0.f;
  f32x4 acc[4][4];
  f32x4 z4 = {0.f, 0.f, 0.f, 0.f};
#pragma unroll
  for (int x = 0; x < 4; ++x)
#pragma unroll
    for (int y = 0; y < 4; ++y) acc[x][y] = z4;

  auto issue = [&](int s) {
    int k0 = s << 5;
    {
      const float4* p = (const float4*)(XT + (size_t)am * n + k0 + (ao << 3));
      a0 = p[0]; a1 = p[1];
      const float4* q = (const float4*)(XT + (size_t)(am + 64) * n + k0 + (ao << 3));
      a2 = q[0]; a3 = q[1];
    }
    if (bok) {
      const float4* p = (const float4*)(H + (size_t)(k0 + bk) * e + j0 + bn);
      b0 = p[0]; b1 = p[1];
      const float4* q = (const float4*)(H + (size_t)(k0 + bk + 16) * e + j0 + bn);
      b2 = q[0]; b3 = q[1];
    } else {
      float4 z = {0.f, 0.f, 0.f, 0.f};
      b0 = z; b1 = z; b2 = z; b3 = z;
    }
  };

  auto stage = [&]() {
    int swz = (am >> 1) & 3;  // same for am+64
    *(us8*)&Al[am * 32 + ((ao ^ swz) << 3)] = cvt8(a0, a1);
    *(us8*)&Al[(am + 64) * 32 + ((ao ^ swz) << 3)] = cvt8(a2, a3);
    int kg0 = (bk >> 3) & 3;
    *(us8*)&Bl[bk * 128 + (bn ^ (kg0 << 4))] = cvt8(b0, b1);
    int k2 = bk + 16, kg1 = (k2 >> 3) & 3;
    *(us8*)&Bl[k2 * 128 + (bn ^ (kg1 << 4))] = cvt8(b2, b3);
    dacc[0] += b0.x + b2.x; dacc[1] += b0.y + b2.y;
    dacc[2] += b0.z + b2.z; dacc[3] += b0.w + b2.w;
    dacc[4] += b1.x + b3.x; dacc[5] += b1.y + b3.y;
    dacc[6] += b1.z + b3.z; dacc[7] += b1.w + b3.w;
  };

  issue(s0);
  for (int s = s0; s < s1; ++s) {
    if (s > s0) __syncthreads();
    stage();
    __syncthreads();
    if (s + 1 < s1) issue(s + 1);
    mfma_step(Al, Bl, wr, wc, ln, lg, acc);
  }

  // C epilogue: atomic accumulate MT[f][j]
#pragma unroll
  for (int mi = 0; mi < 4; ++mi) {
    int fr = (wr << 6) + (mi << 4) + (lg << 2);
#pragma unroll
    for (int ni = 0; ni < 4; ++ni) {
      int j = j0 + (wc << 6) + (ni << 4) + ln;
      if (j < e) {
        f32x4 a = acc[mi][ni];
        atomicAdd(&MT[(size_t)(fr + 0) * e + j], a[0]);
        atomicAdd(&MT[(size_t)(fr + 1) * e + j], a[1]);
        atomicAdd(&MT[(size_t)(fr + 2) * e + j], a[2]);
        atomicAdd(&MT[(size_t)(fr + 3) * e + j], a[3]);
      }
    }
  }
  // deg_e reduce: contributors for column nc*8+cc are the 16 threads with (t&15)==nc
  __syncthreads();
  float* ds = (float*)smem;
#pragma unroll
  for (int c = 0; c < 8; ++c) ds[t * 8 + c] = dacc[c];
  __syncthreads();
  if (t < 128) {
    int nc = t >> 3, cc = t & 7;
    float s = 0.f;
#pragma unroll
    for (int g = 0; g < 16; ++g) s += ds[((g << 4) + nc) * 8 + cc];
    int j = j0 + t;
    if (j < e) atomicAdd(&dege[j], s);
  }
}

// ---- K1b: Mpp[j][nOut] = bf16( inv_de[j] * sum_f MT[f][j] * W[f][nOut] ) ----
__global__ void k_mw(const float* __restrict__ MT, const float* __restrict__ W,
                     const float* __restrict__ dege, unsigned short* __restrict__ Mpp, int e) {
  __shared__ float Ml[128 * 64];
  int t = threadIdx.x;
  int j0 = blockIdx.x << 6;
#pragma unroll
  for (int r = 0; r < 8; ++r) {
    int c = t + (r << 8);
    int f = c >> 4, cc = c & 15;
    *(float4*)&Ml[(f << 6) + (cc << 2)] = *(const float4*)&MT[(size_t)f * e + j0 + (cc << 2)];
  }
  __syncthreads();
  int n0 = (t & 31) << 2;
  int jo = (t >> 5) << 3;
  float a[4][8];
#pragma unroll
  for (int x = 0; x < 4; ++x)
#pragma unroll
    for (int y = 0; y < 8; ++y) a[x][y] = 0.f;
  for (int f = 0; f < 128; ++f) {
    float4 wv = *(const float4*)&W[(f << 7) + n0];
    const float* mrow = &Ml[(f << 6) + jo];
#pragma unroll
    for (int jj = 0; jj < 8; ++jj) {
      float mv = mrow[jj];
      a[0][jj] += wv.x * mv; a[1][jj] += wv.y * mv;
      a[2][jj] += wv.z * mv; a[3][jj] += wv.w * mv;
    }
  }
  float sc[8];
#pragma unroll
  for (int jj = 0; jj < 8; ++jj) sc[jj] = 1.0f / (dege[j0 + jo + jj] + EPS);
#pragma unroll
  for (int jj = 0; jj < 8; ++jj) {
    bf16x4 o;
    o[0] = (__bf16)(a[0][jj] * sc[jj]); o[1] = (__bf16)(a[1][jj] * sc[jj]);
    o[2] = (__bf16)(a[2][jj] * sc[jj]); o[3] = (__bf16)(a[3][jj] * sc[jj]);
    *(us4*)&Mpp[(size_t)(j0 + jo + jj) * 128 + n0] = __builtin_bit_cast(us4, o);
  }
}

// ---- K2: Y[i][c] += H(i-tile x Kslice) * Mpp(Kslice x 128); deg_v += rowsums(H) ----
__global__ __launch_bounds__(256, 2) void k_gemm2(const float* __restrict__ H,
                                                  const unsigned short* __restrict__ Mpp,
                                                  float* __restrict__ Y,
                                                  float* __restrict__ degv, int n, int e) {
  __shared__ __align__(16) unsigned char smem[16384];
  unsigned short* Al = (unsigned short*)smem;
  unsigned short* Bl = (unsigned short*)(smem + 8192);
  const int t = threadIdx.x;
  const int lane = t & 63, ln = lane & 15, lg = lane >> 4;
  const int wid = t >> 6, wr = wid >> 1, wc = wid & 1;
  const int i0 = blockIdx.x << 7;
  const int nsteps = e >> 5;
  const int s0 = (nsteps * (int)blockIdx.y) >> 3;
  const int s1 = (nsteps * ((int)blockIdx.y + 1)) >> 3;

  const int am = t >> 2, ao = t & 3;
  const int bk = t >> 4, bn = (t & 15) << 3;
  const bool a0ok = (i0 + am) < n;
  const bool a1ok = (i0 + am + 64) < n;

  float4 a0, a1, a2, a3;
  us8 mb0, mb1;
  float dv0 = 0.f, dv1 = 0.f;
  f32x4 acc[4][4];
  f32x4 z4 = {0.f, 0.f, 0.f, 0.f};
#pragma unroll
  for (int x = 0; x < 4; ++x)
#pragma unroll
    for (int y = 0; y < 4; ++y) acc[x][y] = z4;

  auto issue = [&](int s) {
    int k0 = s << 5;
    float4 z = {0.f, 0.f, 0.f, 0.f};
    if (a0ok) {
      const float4* p = (const float4*)(H + (size_t)(i0 + am) * e + k0 + (ao << 3));
      a0 = p[0]; a1 = p[1];
    } else { a0 = z; a1 = z; }
    if (a1ok) {
      const float4* q = (const float4*)(H + (size_t)(i0 + am + 64) * e + k0 + (ao << 3));
      a2 = q[0]; a3 = q[1];
    } else { a2 = z; a3 = z; }
    mb0 = *(const us8*)(Mpp + (size_t)(k0 + bk) * 128 + bn);
    mb1 = *(const us8*)(Mpp + (size_t)(k0 + bk + 16) * 128 + bn);
  };

  auto stage = [&]() {
    int swz = (am >> 1) & 3;
    *(us8*)&Al[am * 32 + ((ao ^ swz) << 3)] = cvt8(a0, a1);
    *(us8*)&Al[(am + 64) * 32 + ((ao ^ swz) << 3)] = cvt8(a2, a3);
    dv0 += a0.x + a0.y + a0.z + a0.w + a1.x + a1.y + a1.z + a1.w;
    dv1 += a2.x + a2.y + a2.z + a2.w + a3.x + a3.y + a3.z + a3.w;
    int kg0 = (bk >> 3) & 3;
    *(us8*)&Bl[bk * 128 + (bn ^ (kg0 << 4))] = mb0;
    int k2 = bk + 16, kg1 = (k2 >> 3) & 3;
    *(us8*)&Bl[k2 * 128 + (bn ^ (kg1 << 4))] = mb1;
  };

  issue(s0);
  for (int s = s0; s < s1; ++s) {
    if (s > s0) __syncthreads();
    stage();
    __syncthreads();
    if (s + 1 < s1) issue(s + 1);
    mfma_step(Al, Bl, wr, wc, ln, lg, acc);
  }

#pragma unroll
  for (int mi = 0; mi < 4; ++mi) {
    int ir = i0 + (wr << 6) + (mi << 4) + (lg << 2);
#pragma unroll
    for (int ni = 0; ni < 4; ++ni) {
      int col = (wc << 6) + (ni << 4) + ln;
      f32x4 a = acc[mi][ni];
#pragma unroll
      for (int r = 0; r < 4; ++r)
        if (ir + r < n) atomicAdd(&Y[(size_t)(ir + r) * 128 + col], a[r]);
    }
  }
  // deg_v reduce: 4 contributors (t&3) per row
  __syncthreads();
  float* ds = (float*)smem;
  ds[t] = dv0;
  ds[256 + t] = dv1;
  __syncthreads();
  if (t < 128) {
    float s;
    if (t < 64) s = ds[t * 4] + ds[t * 4 + 1] + ds[t * 4 + 2] + ds[t * 4 + 3];
    else {
      int b = 256 + (t - 64) * 4;
      s = ds[b] + ds[b + 1] + ds[b + 2] + ds[b + 3];
    }
    int i = i0 + t;
    if (i < n) atomicAdd(&degv[i], s);
  }
}

// ---- K4: Y[i][:] *= 1/(deg_v[i]+eps) ----
__global__ void k_scale(float* __restrict__ Y, const float* __restrict__ degv, int n) {
  int idx = blockIdx.x * blockDim.x + threadIdx.x;  // float4 index
  int tot = n << 5;
  if (idx < tot) {
    int row = idx >> 5;
    float s = 1.0f / (degv[row] + EPS);
    float4* p = (float4*)Y;
    float4 v = p[idx];
    v.x *= s; v.y *= s; v.z *= s; v.w *= s;
    p[idx] = v;
  }
}

extern "C" void kernel_launch(void* const* d_in, const int* in_sizes, int n_in,
                              void* d_out, int out_size, void* d_ws, size_t ws_size,
                              hipStream_t stream) {
  (void)n_in; (void)out_size; (void)ws_size;
  const float* X = (const float*)d_in[0];
  const float* H = (const float*)d_in[1];
  const float* W = (const float*)d_in[2];
  int n = in_sizes[0] >> 7;   // 20000
  int e = in_sizes[1] / n;    // 8000
  float* out = (float*)d_out;

  char* ws = (char*)d_ws;
  float* MT = (float*)ws;                                   // 128*e f32
  size_t offMT = (size_t)128 * e * 4;
  float* dege = (float*)(ws + offMT);                       // e f32
  float* degv = dege + e;                                   // n f32
  unsigned short* Mpp = (unsigned short*)(ws + offMT + (size_t)(e + n) * 4);  // e*128 bf16

  float* XT = out;  // reuse d_out as XT scratch; overwritten later

  k_tr<<<dim3(n >> 5, 4), 256, 0, stream>>>(X, XT, n);
  hipMemsetAsync(ws, 0, offMT + (size_t)(e + n) * 4, stream);
  k_gemm1<<<dim3((e + 127) >> 7, 8), 256, 0, stream>>>(XT, H, MT, dege, n, e);
  k_mw<<<e >> 6, 256, 0, stream>>>(MT, W, dege, Mpp, e);
  hipMemsetAsync(out, 0, (size_t)n * 128 * 4, stream);
  k_gemm2<<<dim3((n + 127) >> 7, 8), 256, 0, stream>>>(H, Mpp, out, degv, n, e);
  k_scale<<<(n * 32 + 255) >> 8, 256, 0, stream>>>(out, degv, n);
}